// Round 7
// baseline (3320.485 us; speedup 1.0000x reference)
//
#include <hip/hip_runtime.h>
#include <math.h>

// GRU B=64, T=512, D=512, H=1024 fp32.
// Round 13: synthesis of R10 (cheap flag discovery) + R12 (tag-in-data, no
// producer drain), assigning each mechanism to what it is cheap at:
//  - publish: tid<256 store ONE tagged u32 each ((bf16<<16)|(t+1)) right after
//    gru_h. No hshare, no drain, no arrive RT. Producer-side serial RTs = 0.
//  - consume: OPTIMISTIC batch load + per-u32 tag validation (1 RT when data
//    is already committed -- steady-state common case). On failure: poll a
//    PACKED flag array (64 u32 = 4 lines, lane->flag[lane], one broadcast-
//    friendly load per retry; R10/R12's scattered retries were the cost),
//    then reload the batch once. Correctness rests ONLY on tags (commit-order
//    independent; same induction as R12 which passed).
//  - flag: hint only; tid0 stores after sync#2 (issue-ordered, no drain).
// Verbatim: asm-pinned W (lives in AGPRs per R12's VGPR_Count=112), R1 W
// swizzle, R12 consumer chunk layout + PACKF maps, LDS reduce, gru_h,
// parity double-buffer, shadow x-side MFMA + x prefetch.
#define T_STEPS 512
#define Bb 64
#define Dd 512
#define Hh 1024
#define NBLK 256

typedef __attribute__((ext_vector_type(8))) short short8;
typedef __attribute__((ext_vector_type(4))) float floatx4;
typedef __attribute__((ext_vector_type(4))) unsigned int uint4v;

__device__ __forceinline__ unsigned short f2bf(float f) {
    unsigned u = __float_as_uint(f);
    unsigned r = u + 0x7fffu + ((u >> 16) & 1u);   // RNE
    return (unsigned short)(r >> 16);
}
__device__ __forceinline__ float bf2f(unsigned short h) {
    return __uint_as_float(((unsigned)h) << 16);
}
__device__ __forceinline__ float gru_h(float zs, float rs, float us, float vs,
                                       float bz, float br, float bu, float bv,
                                       float hprev) {
    float z = 1.f / (1.f + __expf(-(zs + bz)));
    float r = 1.f / (1.f + __expf(-(rs + br)));
    float n = 1.f - 2.f / (__expf(2.f * (us + bu + r * (vs + bv))) + 1.f);
    return (1.f - z) * n + z * hprev;
}
__device__ __forceinline__ short8 cvt8(float4 a, float4 b) {
    short8 s;
    s[0] = (short)f2bf(a.x); s[1] = (short)f2bf(a.y);
    s[2] = (short)f2bf(a.z); s[3] = (short)f2bf(a.w);
    s[4] = (short)f2bf(b.x); s[5] = (short)f2bf(b.y);
    s[6] = (short)f2bf(b.z); s[7] = (short)f2bf(b.w);
    return s;
}

// ---------------- setup: VERBATIM round-1-proven W swizzle ----------------
__global__ __launch_bounds__(256) void build_wsw(
    const float* __restrict__ Wzx, const float* __restrict__ Wzh,
    const float* __restrict__ Wrx, const float* __restrict__ Wrh,
    const float* __restrict__ Wnx, const float* __restrict__ Wnh,
    unsigned short* __restrict__ wsw)
{
    int idx = blockIdx.x * 256 + threadIdx.x;   // 589824 total = 2304*256
    int l = idx & 63;
    int rest = idx >> 6;
    int g = rest % 3; rest /= 3;
    int ks = rest % 48;
    int ct = rest / 48;
    if (ct >= 64) return;
    int k0 = ks * 32 + ((l >> 4) << 3);
    int n  = ct * 16 + (l & 15);
    const float* Wx = (g == 0) ? Wzx : (g == 1) ? Wrx : Wnx;
    const float* Wh = (g == 0) ? Wzh : (g == 1) ? Wrh : Wnh;
    const float* src = (k0 < Dd) ? (Wx + (size_t)k0 * Hh + n)
                                 : (Wh + (size_t)(k0 - Dd) * Hh + n);
    size_t base = ((((size_t)ct * 48 + ks) * 3 + g) * 2) * 512;
    unsigned short* hi = wsw + base + l * 8;
    unsigned short* lo = hi + 512;
    #pragma unroll
    for (int j = 0; j < 8; ++j) {
        float w = src[(size_t)j * Hh];
        unsigned short h16 = f2bf(w);
        hi[j] = h16;
        lo[j] = f2bf(w - bf2f(h16));
    }
}

// W register set: 6 k-slices (i=0,1 x-side; i=2..5 h-side) x 6 frags each.
// Loaded once via asm volatile (un-sinkable, un-rematerializable) -> pinned.
#define WDECL(i) uint4v uzh##i, uzl##i, urh##i, url##i, unh##i, unl##i
#define WLOADA(i, ksv) do { \
    const unsigned short* wp = wsw + (size_t)(cb * 48 + (ksv)) * 3072 + lane * 8; \
    asm volatile("global_load_dwordx4 %0, %1, off" : "=&v"(uzh##i) : "v"(wp)        ); \
    asm volatile("global_load_dwordx4 %0, %1, off" : "=&v"(uzl##i) : "v"(wp + 512)  ); \
    asm volatile("global_load_dwordx4 %0, %1, off" : "=&v"(urh##i) : "v"(wp + 1024) ); \
    asm volatile("global_load_dwordx4 %0, %1, off" : "=&v"(url##i) : "v"(wp + 1536) ); \
    asm volatile("global_load_dwordx4 %0, %1, off" : "=&v"(unh##i) : "v"(wp + 2048) ); \
    asm volatile("global_load_dwordx4 %0, %1, off" : "=&v"(unl##i) : "v"(wp + 2560) ); \
} while (0)
#define WS(name) __builtin_bit_cast(short8, name)
#define XMFMA(i, av) do { \
    aZ  = __builtin_amdgcn_mfma_f32_16x16x32_bf16(av, WS(uzh##i), aZ,  0, 0, 0); \
    aZ  = __builtin_amdgcn_mfma_f32_16x16x32_bf16(av, WS(uzl##i), aZ,  0, 0, 0); \
    aR  = __builtin_amdgcn_mfma_f32_16x16x32_bf16(av, WS(urh##i), aR,  0, 0, 0); \
    aR  = __builtin_amdgcn_mfma_f32_16x16x32_bf16(av, WS(url##i), aR,  0, 0, 0); \
    aNx = __builtin_amdgcn_mfma_f32_16x16x32_bf16(av, WS(unh##i), aNx, 0, 0, 0); \
    aNx = __builtin_amdgcn_mfma_f32_16x16x32_bf16(av, WS(unl##i), aNx, 0, 0, 0); } while (0)
#define HMFMA(i, av) do { \
    aZ  = __builtin_amdgcn_mfma_f32_16x16x32_bf16(av, WS(uzh##i), aZ,  0, 0, 0); \
    aZ  = __builtin_amdgcn_mfma_f32_16x16x32_bf16(av, WS(uzl##i), aZ,  0, 0, 0); \
    aR  = __builtin_amdgcn_mfma_f32_16x16x32_bf16(av, WS(urh##i), aR,  0, 0, 0); \
    aR  = __builtin_amdgcn_mfma_f32_16x16x32_bf16(av, WS(url##i), aR,  0, 0, 0); \
    aNh = __builtin_amdgcn_mfma_f32_16x16x32_bf16(av, WS(unh##i), aNh, 0, 0, 0); \
    aNh = __builtin_amdgcn_mfma_f32_16x16x32_bf16(av, WS(unl##i), aNh, 0, 0, 0); } while (0)
#define LOADX(tt) do { const float* xp = xrow + (size_t)(tt) * Dd; \
    xf0 = *(const float4*)(xp);      xf1 = *(const float4*)(xp + 4); \
    xf2 = *(const float4*)(xp + 32); xf3 = *(const float4*)(xp + 36); } while (0)
// pack two tagged-u32 quads into one bf16 A-frag (hi16 of each word)
#define PACKF(dst, lo, hi) do { \
    dst[0] = (short)(lo[0] >> 16); dst[1] = (short)(lo[1] >> 16); \
    dst[2] = (short)(lo[2] >> 16); dst[3] = (short)(lo[3] >> 16); \
    dst[4] = (short)(hi[0] >> 16); dst[5] = (short)(hi[1] >> 16); \
    dst[6] = (short)(hi[2] >> 16); dst[7] = (short)(hi[3] >> 16); } while (0)
#define LOAD8(hq) do { \
    asm volatile("global_load_dwordx4 %0, %1, off sc0 sc1"            : "=&v"(c0) : "v"(hq) : "memory"); \
    asm volatile("global_load_dwordx4 %0, %1, off offset:16 sc0 sc1"  : "=&v"(c1) : "v"(hq) : "memory"); \
    asm volatile("global_load_dwordx4 %0, %1, off offset:128 sc0 sc1" : "=&v"(c2) : "v"(hq) : "memory"); \
    asm volatile("global_load_dwordx4 %0, %1, off offset:144 sc0 sc1" : "=&v"(c3) : "v"(hq) : "memory"); \
    asm volatile("global_load_dwordx4 %0, %1, off offset:256 sc0 sc1" : "=&v"(c4) : "v"(hq) : "memory"); \
    asm volatile("global_load_dwordx4 %0, %1, off offset:272 sc0 sc1" : "=&v"(c5) : "v"(hq) : "memory"); \
    asm volatile("global_load_dwordx4 %0, %1, off offset:384 sc0 sc1" : "=&v"(c6) : "v"(hq) : "memory"); \
    asm volatile("global_load_dwordx4 %0, %1, off offset:400 sc0 sc1" : "=&v"(c7) : "v"(hq) : "memory"); \
    asm volatile("s_waitcnt vmcnt(0)" ::: "memory"); } while (0)
#define VBAD(cv) do { \
    bad |= (cv[0] ^ tagv) & 0xffffu; bad |= (cv[1] ^ tagv) & 0xffffu; \
    bad |= (cv[2] ^ tagv) & 0xffffu; bad |= (cv[3] ^ tagv) & 0xffffu; } while (0)

// ---------------- persistent GRU: tag-validated optimistic exchange ----------------
__global__ __launch_bounds__(512, 2) void gru_persist(
    const float* __restrict__ x,
    const float* __restrict__ bzx, const float* __restrict__ bzh,
    const float* __restrict__ brx, const float* __restrict__ brh,
    const float* __restrict__ bnx, const float* __restrict__ bnh,
    const unsigned short* __restrict__ wsw,
    unsigned* __restrict__ hbuf,          // u32 [2 parity][64 rows][1024 cols]
    unsigned* __restrict__ bar,           // packed flags: 4 chains x 64 u32
    float* __restrict__ out)
{
    __shared__ float part[8][4][64][4];   // [wave][z,r,nx,nh][lane][q]  32 KB

    const int tid  = threadIdx.x;
    const int lane = tid & 63;
    const int wave = tid >> 6;            // 0..7
    const int bx   = blockIdx.x;
    const int rb   = bx >> 6;             // 0..3  (16-row chain)
    const int cb   = bx & 63;             // 0..63 (16-col tile)
    unsigned* flags = bar + (rb << 6);    // 64 packed u32 per chain (4 lines)

    const int R0   = rb << 4;
    const int orow = tid >> 4;            // valid 0..15 for tid<256
    const int ocol = tid & 15;
    const int gcol = (cb << 4) + ocol;
    const int pl   = ((orow & 12) << 2) | ocol;
    const int pq   = orow & 3;
    const float bz  = bzx[gcol] + bzh[gcol];
    const float brr = brx[gcol] + brh[gcol];
    const float bu  = bnx[gcol];          // bias OUTSIDE r-gate (x-side of n)
    const float bv  = bnh[gcol];          // bias INSIDE  r-gate (h-side of n)
    float hprev = 0.f;

    const int arow  = lane & 15;
    const int acol8 = (lane >> 4) << 3;
    const float* xrow = x + (size_t)(R0 + arow) * (T_STEPS * Dd) + wave * 64 + acol8;

    // consumer base: this wave's 128-col slice of its chain's 16 rows (u32)
    const unsigned* qbase = hbuf + ((size_t)(R0 + arow) << 10) + (wave << 7) + acol8;
    // publisher (tid<256): one tagged u32 per thread at [row R0+orow][col gcol]
    unsigned* pdst0 = hbuf + ((size_t)(R0 + orow) << 10) + gcol;

    // ---- one-time W preload: 36 asm-volatile loads -> pinned (AGPR file) ----
    WDECL(0); WDECL(1); WDECL(2); WDECL(3); WDECL(4); WDECL(5);
    WLOADA(0, wave * 2);      WLOADA(1, wave * 2 + 1);
    WLOADA(2, 16 + wave * 4); WLOADA(3, 17 + wave * 4);
    WLOADA(4, 18 + wave * 4); WLOADA(5, 19 + wave * 4);
    asm volatile("s_waitcnt vmcnt(0)" ::: "memory");
    __builtin_amdgcn_sched_barrier(0);

    // ---- prologue: accX for t=0, prefetch x(1) ----
    float4 xf0, xf1, xf2, xf3;
    floatx4 aZ = {0.f,0.f,0.f,0.f}, aR = aZ, aNx = aZ;
    LOADX(0);
    {
        short8 xa0 = cvt8(xf0, xf1), xa1 = cvt8(xf2, xf3);
        XMFMA(0, xa0); XMFMA(1, xa1);
    }
    LOADX(1);

    for (int t = 0; t < T_STEPS; ++t) {
        // ---------- exchange: optimistic load + tag-validate; flag-poll fallback ----------
        const unsigned* hq = qbase + (((size_t)((t & 1) ^ 1)) << 16);
        const unsigned tagv = (unsigned)t;
        uint4v c0, c1, c2, c3, c4, c5, c6, c7;
        for (;;) {
            LOAD8(hq);
            unsigned bad = 0;
            VBAD(c0); VBAD(c1); VBAD(c2); VBAD(c3);
            VBAD(c4); VBAD(c5); VBAD(c6); VBAD(c7);
            if (__all(bad == 0)) break;
            // cheap discovery: packed flags, one broadcast-friendly load/retry
            const unsigned* fpl = flags + lane;
            unsigned fv;
            for (;;) {
                asm volatile("global_load_dword %0, %1, off sc0 sc1\n\t"
                             "s_waitcnt vmcnt(0)"
                             : "=&v"(fv) : "v"(fpl) : "memory");
                if (__all(fv >= tagv)) break;
                __builtin_amdgcn_s_sleep(1);
            }
        }
        __builtin_amdgcn_sched_barrier(0);   // rule #18: keep MFMA below the validated loads

        // ---------- h-side MFMA (24) ----------
        floatx4 aNh = {0.f,0.f,0.f,0.f};
        {
            short8 a0, a1, a2, a3;
            PACKF(a0, c0, c1); PACKF(a1, c2, c3);
            PACKF(a2, c4, c5); PACKF(a3, c6, c7);
            HMFMA(2, a0); HMFMA(3, a1); HMFMA(4, a2); HMFMA(5, a3);
        }

        // ---------- cross-wave reduce in LDS ----------
        *(floatx4*)&part[wave][0][lane][0] = aZ;
        *(floatx4*)&part[wave][1][lane][0] = aR;
        *(floatx4*)&part[wave][2][lane][0] = aNx;
        *(floatx4*)&part[wave][3][lane][0] = aNh;
        __syncthreads();                      // sync #1

        if (tid < 256) {
            float zs = 0.f, rs = 0.f, us = 0.f, vs = 0.f;
            #pragma unroll
            for (int w = 0; w < 8; ++w) {
                zs += part[w][0][pl][pq];
                rs += part[w][1][pl][pq];
                us += part[w][2][pl][pq];
                vs += part[w][3][pl][pq];
            }
            float h = gru_h(zs, rs, us, vs, bz, brr, bu, bv, hprev);
            hprev = h;
            unsigned hv = (((unsigned)f2bf(h)) << 16) | (unsigned)(t + 1);
            unsigned* pdst = pdst0 + (((size_t)(t & 1)) << 16);
            asm volatile("global_store_dword %0, %1, off sc0 sc1"
                         :: "v"(pdst), "v"(hv) : "memory");
        }
        __syncthreads();                      // sync #2 (flag after all stores issued)

        // ---------- hint flag (no drain; correctness is in the tags) ----------
        if (tid == 0) {
            unsigned fv = (unsigned)(t + 1);
            asm volatile("global_store_dword %0, %1, off sc0 sc1"
                         :: "v"(flags + cb), "v"(fv) : "memory");
        }

        // ---------- shadow: x-side work for t+1 (off critical path) ----------
        if (t + 1 < T_STEPS) {
            floatx4 z4 = {0.f,0.f,0.f,0.f};
            aZ = z4; aR = z4; aNx = z4;
            short8 xa0 = cvt8(xf0, xf1), xa1 = cvt8(xf2, xf3);
            XMFMA(0, xa0); XMFMA(1, xa1);
            if (t + 2 < T_STEPS) LOADX(t + 2);
            __builtin_amdgcn_sched_barrier(0);   // keep shadow work here, not sunk past poll
        }
    }

    if (tid < 256)
        out[(size_t)(R0 + orow) * Hh + gcol] = hprev;
}

extern "C" void kernel_launch(void* const* d_in, const int* in_sizes, int n_in,
                              void* d_out, int out_size, void* d_ws, size_t ws_size,
                              hipStream_t stream) {
    const float* x   = (const float*)d_in[0];
    const float* Wzx = (const float*)d_in[1];
    const float* Wzh = (const float*)d_in[2];
    const float* Wrx = (const float*)d_in[3];
    const float* Wrh = (const float*)d_in[4];
    const float* Wnx = (const float*)d_in[5];
    const float* Wnh = (const float*)d_in[6];
    const float* bzx = (const float*)d_in[7];
    const float* bzh = (const float*)d_in[8];
    const float* brx = (const float*)d_in[9];
    const float* brh = (const float*)d_in[10];
    const float* bnx = (const float*)d_in[11];
    const float* bnh = (const float*)d_in[12];

    unsigned char* ws = (unsigned char*)d_ws;
    unsigned* bar  = (unsigned*)ws;                        // 4 chains x 64 u32 packed (4 KB reserved)
    unsigned* hbuf = (unsigned*)(ws + 4096);               // 2 x 64 x 1024 u32 = 512 KB
    unsigned short* wsw = (unsigned short*)(ws + 4096 + 524288); // 18.9 MB
    // total ws use ~19.4 MB

    hipMemsetAsync(bar, 0, 4096, stream);
    hipMemsetAsync(hbuf, 0, (size_t)2 * Bb * Hh * sizeof(unsigned), stream);

    build_wsw<<<2304, 256, 0, stream>>>(Wzx, Wzh, Wrx, Wrh, Wnx, Wnh, wsw);

    gru_persist<<<NBLK, 512, 0, stream>>>(x, bzx, bzh, brx, brh, bnx, bnh,
                                          wsw, hbuf, bar, (float*)d_out);
}

// Round 8
// 2056.294 us; speedup vs baseline: 1.6148x; 1.6148x over previous
//
#include <hip/hip_runtime.h>
#include <math.h>

// GRU B=64, T=512, D=512, H=1024 fp32.
// Round 14: scope fix. FETCH_SIZE forensics on R8/R9 (535 MB vs ~90 MB of
// actual input traffic; WRITE_SIZE 70 MB == exactly the h publish volume)
// prove the sc0sc1 exchange ops were SYSTEM scope -> every handshake hop
// (drain ack, flag commit, poll, h load) was an HBM round-trip. Cross-XCD
// coherence only needs DEVICE scope = sc1 alone (served at Infinity Cache,
// ~2-3x lower latency, no HBM traffic). This round is R9 VERBATIM with the
// five exchange asm sites changed sc0sc1 -> sc1: counter poll load, 4 h-frag
// loads, h publish store. Arrive stays the R9-proven relaxed AGENT fetch_add.
// Ordering invariant unchanged: data stores -> vmcnt(0) drain -> syncthreads
// -> counter add (flag visible => data committed, scope-independent).
// R12/R13 tag-in-data reverted (degenerate retry spinning, +300MB fetch).
#define T_STEPS 512
#define Bb 64
#define Dd 512
#define Hh 1024
#define NBLK 256
#define GRP 8

typedef __attribute__((ext_vector_type(8))) short short8;
typedef __attribute__((ext_vector_type(4))) float floatx4;
typedef __attribute__((ext_vector_type(4))) unsigned int uint4v;

__device__ __forceinline__ unsigned short f2bf(float f) {
    unsigned u = __float_as_uint(f);
    unsigned r = u + 0x7fffu + ((u >> 16) & 1u);   // RNE
    return (unsigned short)(r >> 16);
}
__device__ __forceinline__ float bf2f(unsigned short h) {
    return __uint_as_float(((unsigned)h) << 16);
}
__device__ __forceinline__ float gru_h(float zs, float rs, float us, float vs,
                                       float bz, float br, float bu, float bv,
                                       float hprev) {
    float z = 1.f / (1.f + __expf(-(zs + bz)));
    float r = 1.f / (1.f + __expf(-(rs + br)));
    float n = 1.f - 2.f / (__expf(2.f * (us + bu + r * (vs + bv))) + 1.f);
    return (1.f - z) * n + z * hprev;
}
__device__ __forceinline__ short8 cvt8(float4 a, float4 b) {
    short8 s;
    s[0] = (short)f2bf(a.x); s[1] = (short)f2bf(a.y);
    s[2] = (short)f2bf(a.z); s[3] = (short)f2bf(a.w);
    s[4] = (short)f2bf(b.x); s[5] = (short)f2bf(b.y);
    s[6] = (short)f2bf(b.z); s[7] = (short)f2bf(b.w);
    return s;
}

// ---------------- setup: VERBATIM round-1-proven W swizzle ----------------
__global__ __launch_bounds__(256) void build_wsw(
    const float* __restrict__ Wzx, const float* __restrict__ Wzh,
    const float* __restrict__ Wrx, const float* __restrict__ Wrh,
    const float* __restrict__ Wnx, const float* __restrict__ Wnh,
    unsigned short* __restrict__ wsw)
{
    int idx = blockIdx.x * 256 + threadIdx.x;   // 589824 total = 2304*256
    int l = idx & 63;
    int rest = idx >> 6;
    int g = rest % 3; rest /= 3;
    int ks = rest % 48;
    int ct = rest / 48;
    if (ct >= 64) return;
    int k0 = ks * 32 + ((l >> 4) << 3);
    int n  = ct * 16 + (l & 15);
    const float* Wx = (g == 0) ? Wzx : (g == 1) ? Wrx : Wnx;
    const float* Wh = (g == 0) ? Wzh : (g == 1) ? Wrh : Wnh;
    const float* src = (k0 < Dd) ? (Wx + (size_t)k0 * Hh + n)
                                 : (Wh + (size_t)(k0 - Dd) * Hh + n);
    size_t base = ((((size_t)ct * 48 + ks) * 3 + g) * 2) * 512;
    unsigned short* hi = wsw + base + l * 8;
    unsigned short* lo = hi + 512;
    #pragma unroll
    for (int j = 0; j < 8; ++j) {
        float w = src[(size_t)j * Hh];
        unsigned short h16 = f2bf(w);
        hi[j] = h16;
        lo[j] = f2bf(w - bf2f(h16));
    }
}

// W register set: 6 k-slices (i=0,1 x-side; i=2..5 h-side) x 6 frags each.
// Loaded once via asm volatile (un-sinkable, un-rematerializable) -> pinned.
#define WDECL(i) uint4v uzh##i, uzl##i, urh##i, url##i, unh##i, unl##i
#define WLOADA(i, ksv) do { \
    const unsigned short* wp = wsw + (size_t)(cb * 48 + (ksv)) * 3072 + lane * 8; \
    asm volatile("global_load_dwordx4 %0, %1, off" : "=&v"(uzh##i) : "v"(wp)        ); \
    asm volatile("global_load_dwordx4 %0, %1, off" : "=&v"(uzl##i) : "v"(wp + 512)  ); \
    asm volatile("global_load_dwordx4 %0, %1, off" : "=&v"(urh##i) : "v"(wp + 1024) ); \
    asm volatile("global_load_dwordx4 %0, %1, off" : "=&v"(url##i) : "v"(wp + 1536) ); \
    asm volatile("global_load_dwordx4 %0, %1, off" : "=&v"(unh##i) : "v"(wp + 2048) ); \
    asm volatile("global_load_dwordx4 %0, %1, off" : "=&v"(unl##i) : "v"(wp + 2560) ); \
} while (0)
#define WS(name) __builtin_bit_cast(short8, name)
#define XMFMA(i, av) do { \
    aZ  = __builtin_amdgcn_mfma_f32_16x16x32_bf16(av, WS(uzh##i), aZ,  0, 0, 0); \
    aZ  = __builtin_amdgcn_mfma_f32_16x16x32_bf16(av, WS(uzl##i), aZ,  0, 0, 0); \
    aR  = __builtin_amdgcn_mfma_f32_16x16x32_bf16(av, WS(urh##i), aR,  0, 0, 0); \
    aR  = __builtin_amdgcn_mfma_f32_16x16x32_bf16(av, WS(url##i), aR,  0, 0, 0); \
    aNx = __builtin_amdgcn_mfma_f32_16x16x32_bf16(av, WS(unh##i), aNx, 0, 0, 0); \
    aNx = __builtin_amdgcn_mfma_f32_16x16x32_bf16(av, WS(unl##i), aNx, 0, 0, 0); } while (0)
#define HMFMA(i, av) do { \
    aZ  = __builtin_amdgcn_mfma_f32_16x16x32_bf16(av, WS(uzh##i), aZ,  0, 0, 0); \
    aZ  = __builtin_amdgcn_mfma_f32_16x16x32_bf16(av, WS(uzl##i), aZ,  0, 0, 0); \
    aR  = __builtin_amdgcn_mfma_f32_16x16x32_bf16(av, WS(urh##i), aR,  0, 0, 0); \
    aR  = __builtin_amdgcn_mfma_f32_16x16x32_bf16(av, WS(url##i), aR,  0, 0, 0); \
    aNh = __builtin_amdgcn_mfma_f32_16x16x32_bf16(av, WS(unh##i), aNh, 0, 0, 0); \
    aNh = __builtin_amdgcn_mfma_f32_16x16x32_bf16(av, WS(unl##i), aNh, 0, 0, 0); } while (0)
#define LOADX(tt) do { const float* xp = xrow + (size_t)(tt) * Dd; \
    xf0 = *(const float4*)(xp);      xf1 = *(const float4*)(xp + 4); \
    xf2 = *(const float4*)(xp + 32); xf3 = *(const float4*)(xp + 36); } while (0)

// ---------------- persistent GRU: W pinned, device-scope (sc1) exchange ----------------
__global__ __launch_bounds__(512, 2) void gru_persist(
    const float* __restrict__ x,
    const float* __restrict__ bzx, const float* __restrict__ bzh,
    const float* __restrict__ brx, const float* __restrict__ brh,
    const float* __restrict__ bnx, const float* __restrict__ bnh,
    const unsigned short* __restrict__ wsw,
    unsigned short* __restrict__ hbuf,
    unsigned* __restrict__ bar,
    float* __restrict__ out)
{
    __shared__ float part[8][4][64][4];   // [wave][z,r,nx,nh][lane][q]  32 KB

    const int tid  = threadIdx.x;
    const int lane = tid & 63;
    const int wave = tid >> 6;            // 0..7
    const int bx   = blockIdx.x;
    const int rb   = bx >> 6;             // 0..3  (16-row chain)
    const int cb   = bx & 63;             // 0..63 (16-col tile)
    unsigned* cnt  = bar + (rb << 6);     // flat per-chain counter, 256 B apart

    const int R0   = rb << 4;
    const int orow = tid >> 4;            // valid 0..15 for tid<256
    const int ocol = tid & 15;
    const int gcol = (cb << 4) + ocol;
    const int pl   = ((orow & 12) << 2) | ocol;
    const int pq   = orow & 3;
    const float bz  = bzx[gcol] + bzh[gcol];
    const float brr = brx[gcol] + brh[gcol];
    const float bu  = bnx[gcol];          // bias OUTSIDE r-gate (x-side of n)
    const float bv  = bnh[gcol];          // bias INSIDE  r-gate (h-side of n)
    float hprev = 0.f;

    const int arow  = lane & 15;
    const int acol8 = (lane >> 4) << 3;
    const float* xrow = x + (size_t)(R0 + arow) * (T_STEPS * Dd) + wave * 64 + acol8;

    // ---- one-time W preload: 36 asm-volatile loads -> pinned (unified RF) ----
    WDECL(0); WDECL(1); WDECL(2); WDECL(3); WDECL(4); WDECL(5);
    WLOADA(0, wave * 2);      WLOADA(1, wave * 2 + 1);
    WLOADA(2, 16 + wave * 4); WLOADA(3, 17 + wave * 4);
    WLOADA(4, 18 + wave * 4); WLOADA(5, 19 + wave * 4);
    asm volatile("s_waitcnt vmcnt(0)" ::: "memory");
    __builtin_amdgcn_sched_barrier(0);

    // ---- prologue: accX for t=0, prefetch x(1) ----
    float4 xf0, xf1, xf2, xf3;
    floatx4 aZ = {0.f,0.f,0.f,0.f}, aR = aZ, aNx = aZ;
    LOADX(0);
    {
        short8 xa0 = cvt8(xf0, xf1), xa1 = cvt8(xf2, xf3);
        XMFMA(0, xa0); XMFMA(1, xa1);
    }
    LOADX(1);

    for (int t = 0; t < T_STEPS; ++t) {
        // ---------- wait: all 64 chain blocks arrived t times (sc1 = device scope) ----------
        if (t) {
            __syncthreads();
            if (tid == 0) {
                const unsigned target = (unsigned)t * 64u;
                const unsigned* cp = cnt;
                unsigned v;
                for (;;) {
                    asm volatile("global_load_dword %0, %1, off sc1\n\t"
                                 "s_waitcnt vmcnt(0)"
                                 : "=&v"(v) : "v"(cp) : "memory");
                    if (v >= target) break;
                    __builtin_amdgcn_s_sleep(1);
                }
            }
            __syncthreads();
        }

        // ---------- h(t-1) device-scope loads (Infinity Cache, not HBM) ----------
        const unsigned short* hrow = hbuf
            + ((size_t)((((t & 1) ^ 1) * Bb) + R0 + arow) << 10)
            + (wave << 7) + acol8;
        uint4v h0, h1, h2, h3;
        asm volatile("global_load_dwordx4 %0, %1, off sc1"            : "=&v"(h0) : "v"(hrow) : "memory");
        asm volatile("global_load_dwordx4 %0, %1, off offset:64 sc1"  : "=&v"(h1) : "v"(hrow) : "memory");
        asm volatile("global_load_dwordx4 %0, %1, off offset:128 sc1" : "=&v"(h2) : "v"(hrow) : "memory");
        asm volatile("global_load_dwordx4 %0, %1, off offset:192 sc1" : "=&v"(h3) : "v"(hrow) : "memory");
        asm volatile("s_waitcnt vmcnt(0)" ::: "memory");
        __builtin_amdgcn_sched_barrier(0);   // rule #18: don't hoist MFMA above waitcnt

        // ---------- h-side MFMA (24) ----------
        floatx4 aNh = {0.f,0.f,0.f,0.f};
        {
            short8 a0 = __builtin_bit_cast(short8, h0);
            short8 a1 = __builtin_bit_cast(short8, h1);
            short8 a2 = __builtin_bit_cast(short8, h2);
            short8 a3 = __builtin_bit_cast(short8, h3);
            HMFMA(2, a0); HMFMA(3, a1); HMFMA(4, a2); HMFMA(5, a3);
        }

        // ---------- cross-wave reduce in LDS ----------
        *(floatx4*)&part[wave][0][lane][0] = aZ;
        *(floatx4*)&part[wave][1][lane][0] = aR;
        *(floatx4*)&part[wave][2][lane][0] = aNx;
        *(floatx4*)&part[wave][3][lane][0] = aNh;
        __syncthreads();

        if (tid < 256) {
            float zs = 0.f, rs = 0.f, us = 0.f, vs = 0.f;
            #pragma unroll
            for (int w = 0; w < 8; ++w) {
                zs += part[w][0][pl][pq];
                rs += part[w][1][pl][pq];
                us += part[w][2][pl][pq];
                vs += part[w][3][pl][pq];
            }
            float h = gru_h(zs, rs, us, vs, bz, brr, bu, bv, hprev);
            hprev = h;
            unsigned hv = (unsigned)f2bf(h);
            const unsigned short* hptr = hbuf
                + ((size_t)((t & 1) * Bb + R0 + orow) << 10) + gcol;
            asm volatile("global_store_short %0, %1, off sc1"
                         :: "v"(hptr), "v"(hv) : "memory");
        }
        // drain this wave's stores to the coherence point, then block-wide order
        asm volatile("s_waitcnt vmcnt(0)" ::: "memory");
        __syncthreads();

        // ---------- arrive (relaxed agent RMW, R8/R9-proven) ----------
        if (tid == 0)
            __hip_atomic_fetch_add(cnt, 1u, __ATOMIC_RELAXED, __HIP_MEMORY_SCOPE_AGENT);

        // ---------- shadow: x-side work for t+1 (off critical path) ----------
        if (t + 1 < T_STEPS) {
            floatx4 z4 = {0.f,0.f,0.f,0.f};
            aZ = z4; aR = z4; aNx = z4;
            short8 xa0 = cvt8(xf0, xf1), xa1 = cvt8(xf2, xf3);
            XMFMA(0, xa0); XMFMA(1, xa1);
            if (t + 2 < T_STEPS) LOADX(t + 2);
            __builtin_amdgcn_sched_barrier(0);   // keep shadow work here, not sunk past wait
        }
    }

    if (tid < 256)
        out[(size_t)(R0 + orow) * Hh + gcol] = hprev;
}

extern "C" void kernel_launch(void* const* d_in, const int* in_sizes, int n_in,
                              void* d_out, int out_size, void* d_ws, size_t ws_size,
                              hipStream_t stream) {
    const float* x   = (const float*)d_in[0];
    const float* Wzx = (const float*)d_in[1];
    const float* Wzh = (const float*)d_in[2];
    const float* Wrx = (const float*)d_in[3];
    const float* Wrh = (const float*)d_in[4];
    const float* Wnx = (const float*)d_in[5];
    const float* Wnh = (const float*)d_in[6];
    const float* bzx = (const float*)d_in[7];
    const float* bzh = (const float*)d_in[8];
    const float* brx = (const float*)d_in[9];
    const float* brh = (const float*)d_in[10];
    const float* bnx = (const float*)d_in[11];
    const float* bnh = (const float*)d_in[12];

    unsigned char* ws = (unsigned char*)d_ws;
    unsigned* bar = (unsigned*)ws;                               // 4 KB (4 chains x 256 B)
    unsigned short* hbuf = (unsigned short*)(ws + 4096);         // 2 x 64 x 1024 bf16 = 256 KB
    unsigned short* wsw  = (unsigned short*)(ws + 4096 + 262144);// 18.9 MB
    // total ws use ~19.2 MB

    hipMemsetAsync(bar, 0, 4096, stream);
    hipMemsetAsync(hbuf, 0, (size_t)2 * Bb * Hh * sizeof(unsigned short), stream);

    build_wsw<<<2304, 256, 0, stream>>>(Wzx, Wzh, Wrx, Wrh, Wnx, Wnh, wsw);

    gru_persist<<<NBLK, 512, 0, stream>>>(x, bzx, bzh, brx, brh, bnx, bnh,
                                          wsw, hbuf, bar, (float*)d_out);
}